// Round 7
// baseline (506.123 us; speedup 1.0000x reference)
//
#include <hip/hip_runtime.h>
#include <math.h>

#define H  14
#define C  7
#define HC 98
#define FIN 256
#define NEG_SLOPE 0.2f
#define LOG2E 1.44269504088896f

#define BSHIFT 9
#define BSIZE  512
#define NBUCK_MAX 256

typedef __attribute__((ext_vector_type(8))) short short8;
typedef __attribute__((ext_vector_type(4))) float floatx4;
typedef _Float16 h2 __attribute__((ext_vector_type(2)));

#define WT_ROWS   112            // 98 cols zero-padded to 7*16
#define WT_STRIDE 264            // 256 + 8 pad (bf16 units)
#define VS_STRIDE 99             // 98 + 1 pad (f32 units)

// ---- fp16 helpers via native _Float16 vectors (no hip_fp16.h dependence) ----
__device__ __forceinline__ h2 u2h(unsigned u) { return __builtin_bit_cast(h2, u); }
__device__ __forceinline__ unsigned hpk(float a, float b) {
    h2 v = { (_Float16)a, (_Float16)b };
    return __builtin_bit_cast(unsigned, v);
}
__device__ __forceinline__ float hhi(unsigned w) {
    unsigned short s = (unsigned short)(w >> 16);
    return (float)__builtin_bit_cast(_Float16, s);
}
// max-combine of packed fp16 pair across lanes (xor mask)
__device__ __forceinline__ h2 hshfl_max(h2 v, int mask) {
    int u = __builtin_bit_cast(int, v);
    int o = __shfl_xor(u, mask, 64);
    return __builtin_elementwise_max(v, u2h((unsigned)o));
}

// ---------------- direct CSR construction (no pedge, no self loops) ----------------
// deg/gcnt zeroed by hipMemsetAsync before launch.

__global__ __launch_bounds__(256) void k_deg(const int* __restrict__ ei, int E,
                                             int* __restrict__ deg,
                                             int* __restrict__ gcnt, int nb) {
    __shared__ int hist[NBUCK_MAX];
    const int t = threadIdx.x;
    for (int i = t; i < nb; i += 256) hist[i] = 0;
    __syncthreads();
    const int stride = gridDim.x * 256;
    for (int e = blockIdx.x * 256 + t; e < E; e += stride) {
        int d = ei[E + e];
        atomicAdd(deg + d, 1);
        atomicAdd(&hist[d >> BSHIFT], 1);
    }
    __syncthreads();
    for (int i = t; i < nb; i += 256)
        if (hist[i]) atomicAdd(gcnt + i, hist[i]);
}

__global__ __launch_bounds__(1024) void k_bscan(const int* __restrict__ gcnt,
                                                int* __restrict__ boff,
                                                int* __restrict__ row_ptr, int nb, int N) {
    __shared__ int sd[1024];
    int t = threadIdx.x;
    int own = (t < nb) ? gcnt[t] : 0;
    sd[t] = own;
    __syncthreads();
    #pragma unroll
    for (int off = 1; off < 1024; off <<= 1) {
        int v = (t >= off) ? sd[t - off] : 0;
        __syncthreads();
        sd[t] += v;
        __syncthreads();
    }
    if (t < nb) {
        boff[t + 1] = sd[t];
        if (t == nb - 1) row_ptr[N] = sd[t];
    }
    if (t == 0) boff[0] = 0;
}

__global__ __launch_bounds__(512) void k_rowptr(const int* __restrict__ deg,
                                                const int* __restrict__ boff,
                                                int* __restrict__ row_ptr,
                                                int* __restrict__ cur, int N) {
    __shared__ int sc[BSIZE];
    const int b = blockIdx.x;
    const int t = threadIdx.x;
    const int base = b << BSHIFT;
    const int nv = min(BSIZE, N - base);
    int d = (t < nv) ? deg[base + t] : 0;
    sc[t] = d;
    __syncthreads();
    #pragma unroll
    for (int off = 1; off < BSIZE; off <<= 1) {
        int v = (t >= off) ? sc[t - off] : 0;
        __syncthreads();
        sc[t] += v;
        __syncthreads();
    }
    if (t < nv) {
        int rp = boff[b] + sc[t] - d;    // exclusive
        row_ptr[base + t] = rp;
        cur[base + t] = rp;
    }
}

__global__ __launch_bounds__(256) void k_fill(const int* __restrict__ ei, int E,
                                              int* __restrict__ cur, int* __restrict__ col) {
    const int stride = gridDim.x * 256;
    for (int e = blockIdx.x * 256 + threadIdx.x; e < E; e += stride) {
        int s = ei[e], d = ei[E + e];
        int pos = atomicAdd(cur + d, 1);
        col[pos] = s;                    // row-internal order arbitrary (max/sum agg)
    }
}

// ---------------- layer-1: MFMA projection fused with pack ----------------

__global__ void k_convW(const float* __restrict__ W, unsigned short* __restrict__ WtG) {
    int id = blockIdx.x * blockDim.x + threadIdx.x;   // 112*256
    int n = id >> 8, k = id & 255;
    float v = (n < HC) ? W[k * HC + n] : 0.f;
    WtG[id] = (unsigned short)(__float_as_uint(v) >> 16);  // exact: inputs bf16-rounded
}

// Barrier-free K-loop: A-fragments loaded global->reg per lane (no x staging,
// no per-step barriers). Weights staged once in LDS; LDS reused for the
// output transpose after the K-loop.
// xpack[n*H+h] = {7 msg fp16, src-logit*log2e fp16}; aldst = dst logit*log2e.
__global__ __launch_bounds__(256) void k_proj1_mfma(
    const float* __restrict__ x, const unsigned short* __restrict__ WtG,
    const float* __restrict__ asrc, const float* __restrict__ adst,
    uint4* __restrict__ xpack, float* __restrict__ aldst, int N)
{
    __shared__ unsigned short wt_s[WT_ROWS * WT_STRIDE];  // 59136 B (reused as f32 vals)
    __shared__ float as_s[HC], ad_s[HC];
    float* vals_s = (float*)wt_s;                          // 64*99*4 = 25344 B < 59136
    const int t  = threadIdx.x;
    const int wv = t >> 6;
    const int l  = t & 63;
    const int ln = l & 15;
    const int qd = l >> 4;
    const int rowBase = blockIdx.x * 64;

    #pragma unroll
    for (int i = 0; i < 14; ++i) {
        int f = i * 256 + t;            // uint4 index, 3584 total (32 per row)
        int r = f >> 5, pos = f & 31;
        *(uint4*)(wt_s + r * WT_STRIDE + pos * 8) = ((const uint4*)WtG)[f];
    }
    if (t < HC) { as_s[t] = asrc[t]; ad_s[t] = adst[t]; }
    __syncthreads();

    // my MFMA A-row: rowBase + wv*16 + ln (clamped; pack loop guards gn >= N)
    int gr = rowBase + (wv << 4) + ln; if (gr >= N) gr = N - 1;
    const float* xr = x + (size_t)gr * FIN;

    // load all 8 steps' A-fragments: step s -> cols s*32 + qd*8 .. +7
    short8 afr[8];
    #pragma unroll
    for (int s = 0; s < 8; ++s) {
        float4 v0 = *(const float4*)(xr + s * 32 + qd * 8);
        float4 v1 = *(const float4*)(xr + s * 32 + qd * 8 + 4);
        short8 a;
        a[0] = (short)(__float_as_uint(v0.x) >> 16);
        a[1] = (short)(__float_as_uint(v0.y) >> 16);
        a[2] = (short)(__float_as_uint(v0.z) >> 16);
        a[3] = (short)(__float_as_uint(v0.w) >> 16);
        a[4] = (short)(__float_as_uint(v1.x) >> 16);
        a[5] = (short)(__float_as_uint(v1.y) >> 16);
        a[6] = (short)(__float_as_uint(v1.z) >> 16);
        a[7] = (short)(__float_as_uint(v1.w) >> 16);
        afr[s] = a;
    }

    floatx4 acc[7] = {};
    #pragma unroll
    for (int s = 0; s < 8; ++s) {
        const int k0 = s * 32;
        #pragma unroll
        for (int ct = 0; ct < 7; ++ct) {
            short8 b = *(const short8*)(wt_s + (ct * 16 + ln) * WT_STRIDE + k0 + qd * 8);
            acc[ct] = __builtin_amdgcn_mfma_f32_16x16x32_bf16(afr[s], b, acc[ct], 0, 0, 0);
        }
    }

    __syncthreads();                    // all waves done with wt_s; reuse as vals_s
    // C/D: col = ln, row = qd*4 + r (local row = wv*16 + qd*4 + r)
    #pragma unroll
    for (int ct = 0; ct < 7; ++ct) {
        int colg = ct * 16 + ln;
        if (colg < HC) {
            #pragma unroll
            for (int r = 0; r < 4; ++r)
                vals_s[((wv << 4) + (qd << 2) + r) * VS_STRIDE + colg] = acc[ct][r];
        }
    }
    __syncthreads();

    // pack: 64 nodes x 14 heads = 896 records
    for (int p = t; p < 64 * H; p += 256) {
        int nl = p / H, h = p - nl * H;
        int gn = rowBase + nl;
        if (gn >= N) break;
        const float* vp = vals_s + nl * VS_STRIDE + h * C;
        float v[C];
        float s1 = 0.f, s2 = 0.f;
        #pragma unroll
        for (int c2 = 0; c2 < C; ++c2) {
            float f = vp[c2];
            v[c2] = f;
            s1 = fmaf(f, as_s[h * C + c2], s1);
            s2 = fmaf(f, ad_s[h * C + c2], s2);
        }
        uint4 pk;
        pk.x = hpk(v[0], v[1]);
        pk.y = hpk(v[2], v[3]);
        pk.z = hpk(v[4], v[5]);
        pk.w = hpk(v[6], s1 * LOG2E);
        xpack[(size_t)gn * H + h] = pk;
        aldst[(size_t)gn * H + h] = s2 * LOG2E;
    }
}

// ---------------- layer-2 projection + pack (thread per node) ----------------

__global__ __launch_bounds__(256) void k_proj2_pack(
    const float* __restrict__ h1, const float* __restrict__ W,
    const float* __restrict__ asrc, const float* __restrict__ adst,
    uint4* __restrict__ xpack, float* __restrict__ aldst, int N)
{
    __shared__ float Ws[C * HC];
    __shared__ float as_s[HC], ad_s[HC];
    const int t = threadIdx.x;
    for (int i = t; i < C * HC; i += 256) Ws[i] = W[i];
    if (t < HC) { as_s[t] = asrc[t]; ad_s[t] = adst[t]; }
    __syncthreads();
    int n = blockIdx.x * 256 + t;
    if (n >= N) return;
    float xr[C];
    #pragma unroll
    for (int c2 = 0; c2 < C; ++c2) xr[c2] = h1[(size_t)n * C + c2];
    #pragma unroll
    for (int h = 0; h < H; ++h) {
        float v[C], s1 = 0.f, s2 = 0.f;
        #pragma unroll
        for (int c2 = 0; c2 < C; ++c2) {
            float acc = 0.f;
            #pragma unroll
            for (int k = 0; k < C; ++k)
                acc = fmaf(xr[k], Ws[k * HC + h * C + c2], acc);
            v[c2] = acc;
            s1 = fmaf(acc, as_s[h * C + c2], s1);
            s2 = fmaf(acc, ad_s[h * C + c2], s2);
        }
        uint4 pk;
        pk.x = hpk(v[0], v[1]);
        pk.y = hpk(v[2], v[3]);
        pk.z = hpk(v[4], v[5]);
        pk.w = hpk(v[6], s1 * LOG2E);
        xpack[(size_t)n * H + h] = pk;     // 224 B contiguous per thread
        aldst[(size_t)n * H + h] = s2 * LOG2E;
    }
}

// ---------------- fused aggregation: ONE WAVE PER NODE ----------------
// lane = e4*16 + h: e4 in 0..3 = edge slot, h in 0..15 = head (h<14 active).
// Fixed shift K = leaky(ld+2) makes softmax state LINEAR: partial den sums
// and partial channel-maxes combine across edge slots via shfl_xor(16,32);
// head-mean then reduces via shfl_xor(1,2,4,8). No LDS, no __syncthreads.
// col[] is padded by 64 zeroed ints past E, so prefetch needs no clamping:
// overreads hit in-array entries (next row / node 0) and are discarded.
#define AGG_STEP(DEN, REC)                                              \
    {                                                                   \
        float l = hhi((REC).w) + ld;                                    \
        float p = __builtin_amdgcn_exp2f(fmaxf(l, 0.2f * l) - K);       \
        DEN += p;                                                       \
        _Float16 ph = (_Float16)p;                                      \
        h2 p2 = { ph, ph };                                             \
        m0 = __builtin_elementwise_max(m0, p2 * u2h((REC).x));          \
        m1 = __builtin_elementwise_max(m1, p2 * u2h((REC).y));          \
        m2 = __builtin_elementwise_max(m2, p2 * u2h((REC).z));          \
        m3 = __builtin_elementwise_max(m3, p2 * u2h((REC).w));          \
    }

template<int LAYER>
__global__ __launch_bounds__(256) void k_agg(
    const int* __restrict__ row_ptr, const int* __restrict__ col,
    const uint4* __restrict__ xpack, const float* __restrict__ aldst,
    const float* __restrict__ bias,
    float* __restrict__ h1, float* __restrict__ out, int N)
{
    const int t    = threadIdx.x;
    const int lane = t & 63;
    const int e4   = lane >> 4;          // edge slot 0..3
    const int h    = lane & 15;          // head slot (active if < 14)
    const int n    = blockIdx.x * 4 + (t >> 6);
    const bool act = (h < H) && (n < N);

    float den = 0.f, den2 = 0.f;
    h2 m0 = u2h(0xFC00FC00u), m1 = m0, m2 = m0, m3 = m0;   // -inf packed
    float ld = 0.f, K = 0.f;

    if (act) {
        const int e0  = row_ptr[n];
        const int deg = row_ptr[n + 1] - e0;
        ld = aldst[(unsigned)n * H + h];                   // already * log2e
        float kb = ld + 2.0f * LOG2E;
        K = fmaxf(kb, 0.2f * kb);                          // leaky(ld+2), log2 domain

        if (e4 == 0) {                                     // implicit self loop (once)
            uint4 pk = xpack[(unsigned)n * H + h];
            float l = hhi(pk.w) + ld;
            float p = __builtin_amdgcn_exp2f(fmaxf(l, 0.2f * l) - K);
            den = p;
            _Float16 ph = (_Float16)p;
            h2 p2 = { ph, ph };
            m0 = p2 * u2h(pk.x);
            m1 = p2 * u2h(pk.y);
            m2 = p2 * u2h(pk.z);
            m3 = p2 * u2h(pk.w);                           // hi half ignored later
        }

        if (deg > 0) {
            const int* cp = col + e0;
            int i = e4;                                    // edges i = e4 + 4k
            int c0 = cp[i];
            int c1 = cp[i + 4];
            uint4 r0 = xpack[(unsigned)c0 * H + h];
            uint4 r1 = xpack[(unsigned)c1 * H + h];
            c0 = cp[i + 8];
            c1 = cp[i + 12];
            for (; i < deg; i += 8) {
                uint4 curA = r0, curB = r1;
                r0 = xpack[(unsigned)c0 * H + h];
                r1 = xpack[(unsigned)c1 * H + h];
                c0 = cp[i + 16];
                c1 = cp[i + 20];
                AGG_STEP(den,  curA);                      // edge i
                if (i + 4 < deg) AGG_STEP(den2, curB);     // edge i+4
            }
        }
    }
    den += den2;

    // ---- combine across edge slots (lanes h, h+16, h+32, h+48) ----
    den += __shfl_xor(den, 16, 64);
    den += __shfl_xor(den, 32, 64);
    m0 = hshfl_max(m0, 16); m0 = hshfl_max(m0, 32);
    m1 = hshfl_max(m1, 16); m1 = hshfl_max(m1, 32);
    m2 = hshfl_max(m2, 16); m2 = hshfl_max(m2, 32);
    m3 = hshfl_max(m3, 16); m3 = hshfl_max(m3, 32);

    float v[C];
    if (act) {
        float rd = 1.f / den;                              // den >= p_self > 0
        v[0] = (float)m0.x * rd; v[1] = (float)m0.y * rd;
        v[2] = (float)m1.x * rd; v[3] = (float)m1.y * rd;
        v[4] = (float)m2.x * rd; v[5] = (float)m2.y * rd;
        v[6] = (float)m3.x * rd;
    } else {
        #pragma unroll
        for (int c = 0; c < C; ++c) v[c] = 0.f;
    }

    // ---- head mean across 16-lane group ----
    #pragma unroll
    for (int off = 1; off <= 8; off <<= 1) {
        #pragma unroll
        for (int c = 0; c < C; ++c) v[c] += __shfl_xor(v[c], off, 64);
    }

    if (n >= N) return;
    if (LAYER == 1) {
        if (lane < C) {
            float myv = v[0];
            #pragma unroll
            for (int c = 1; c < C; ++c) if (lane == c) myv = v[c];
            h1[(size_t)n * C + lane] = fmaxf(myv * (1.f / H) + bias[lane], 0.f);
        }
    } else {
        float o[C];
        #pragma unroll
        for (int c = 0; c < C; ++c) o[c] = v[c] * (1.f / H) + bias[c];
        float mv = o[0];
        #pragma unroll
        for (int c = 1; c < C; ++c) mv = fmaxf(mv, o[c]);
        float lse = 0.f;
        #pragma unroll
        for (int c = 0; c < C; ++c) lse += __expf(o[c] - mv);
        lse = logf(lse);
        if (lane < C) {
            float myo = o[0];
            #pragma unroll
            for (int c = 1; c < C; ++c) if (lane == c) myo = o[c];
            out[(size_t)n * C + lane] = myo - mv - lse;
        }
    }
}

// ---------------- launch ----------------

static inline size_t align16(size_t v) { return (v + 15) & ~(size_t)15; }

extern "C" void kernel_launch(void* const* d_in, const int* in_sizes, int n_in,
                              void* d_out, int out_size, void* d_ws, size_t ws_size,
                              hipStream_t stream)
{
    const float* x     = (const float*)d_in[0];
    const int*   ei    = (const int*)d_in[1];
    const float* W1    = (const float*)d_in[2];
    const float* asrc1 = (const float*)d_in[3];
    const float* adst1 = (const float*)d_in[4];
    const float* b1    = (const float*)d_in[5];
    const float* W2    = (const float*)d_in[6];
    const float* asrc2 = (const float*)d_in[7];
    const float* adst2 = (const float*)d_in[8];
    const float* b2    = (const float*)d_in[9];

    const int N  = in_sizes[0] / FIN;   // 100000
    const int E  = in_sizes[1] / 2;     // 1600000
    const int nb = (N + BSIZE - 1) >> BSHIFT;   // 196

    char* w = (char*)d_ws;
    uint4* xpack   = (uint4*)w; w += align16((size_t)N * H * 16);   // 22.4 MB
    float* aldst   = (float*)w; w += align16((size_t)N * H * 4);    //  5.6 MB
    float* h1      = (float*)w; w += align16((size_t)N * C * 4);    //  2.8 MB
    int*   row_ptr = (int*)w;   w += align16((size_t)(N + 1) * 4);
    int*   col     = (int*)w;   w += align16((size_t)(E + 64) * 4); //  6.4 MB + pad
    int*   deg     = (int*)w;   w += align16((size_t)(N + nb) * 4); // deg + gcnt contiguous
    int*   cur     = (int*)w;   w += align16((size_t)N * 4);
    int*   boff    = (int*)w;   w += align16((size_t)(nb + 1) * 4);
    unsigned short* WtG = (unsigned short*)w; w += align16((size_t)WT_ROWS * FIN * 2);
    int* gcnt = deg + N;

    const int gAgg  = (N + 3) / 4;      // one wave per node, 4 waves/block
    const int gMfma = (N + 63) / 64;
    const int g256N = (N + 255) / 256;

    // ---- direct CSR build (no self loops; rebuilt every call) ----
    hipMemsetAsync(deg, 0, (size_t)(N + nb) * 4, stream);   // deg + gcnt
    hipMemsetAsync(col + E, 0, 64 * 4, stream);             // prefetch pad
    k_deg<<<256, 256, 0, stream>>>(ei, E, deg, gcnt, nb);
    k_bscan<<<1, 1024, 0, stream>>>(gcnt, boff, row_ptr, nb, N);
    k_rowptr<<<nb, 512, 0, stream>>>(deg, boff, row_ptr, cur, N);
    k_fill<<<256, 256, 0, stream>>>(ei, E, cur, col);

    // ---- layer 1 ----
    k_convW<<<(WT_ROWS * FIN + 255) / 256, 256, 0, stream>>>(W1, WtG);
    k_proj1_mfma<<<gMfma, 256, 0, stream>>>(x, WtG, asrc1, adst1, xpack, aldst, N);
    k_agg<1><<<gAgg, 256, 0, stream>>>(row_ptr, col, xpack, aldst, b1,
                                       h1, (float*)d_out, N);
    // ---- layer 2 ----
    k_proj2_pack<<<g256N, 256, 0, stream>>>(h1, W2, asrc2, adst2, xpack, aldst, N);
    k_agg<2><<<gAgg, 256, 0, stream>>>(row_ptr, col, xpack, aldst, b2,
                                       h1, (float*)d_out, N);
}

// Round 8
// 457.151 us; speedup vs baseline: 1.1071x; 1.1071x over previous
//
#include <hip/hip_runtime.h>
#include <math.h>

#define H  14
#define C  7
#define HC 98
#define FIN 256
#define NEG_SLOPE 0.2f
#define LOG2E 1.44269504088896f

#define BSHIFT 9
#define BSIZE  512
#define NBUCK_MAX 256

typedef __attribute__((ext_vector_type(8))) short short8;
typedef __attribute__((ext_vector_type(4))) float floatx4;
typedef _Float16 h2 __attribute__((ext_vector_type(2)));

#define WT_ROWS   112            // 98 cols zero-padded to 7*16
#define VS_STRIDE 99             // 98 + 1 pad (f32 units)

// ---- fp16 helpers via native _Float16 vectors (no hip_fp16.h dependence) ----
__device__ __forceinline__ h2 u2h(unsigned u) { return __builtin_bit_cast(h2, u); }
__device__ __forceinline__ unsigned hpk(float a, float b) {
    h2 v = { (_Float16)a, (_Float16)b };
    return __builtin_bit_cast(unsigned, v);
}
__device__ __forceinline__ float hhi(unsigned w) {
    unsigned short s = (unsigned short)(w >> 16);
    return (float)__builtin_bit_cast(_Float16, s);
}
// max-combine of packed fp16 pair across lanes (xor mask)
__device__ __forceinline__ h2 hshfl_max(h2 v, int mask) {
    int u = __builtin_bit_cast(int, v);
    int o = __shfl_xor(u, mask, 64);
    return __builtin_elementwise_max(v, u2h((unsigned)o));
}

// ---------------- bucketed CSR construction (no self loops) ----------------

__global__ void k_zero2(int* __restrict__ a, int na, int* __restrict__ b, int nbb) {
    int i = blockIdx.x * blockDim.x + threadIdx.x;
    if (i < na) a[i] = 0;
    if (i < nbb) b[i] = 0;
}

__global__ __launch_bounds__(256) void k_hist(const int* __restrict__ ei, int E,
                                              int* __restrict__ gcnt, int nb) {
    __shared__ int hist[NBUCK_MAX];
    const int t = threadIdx.x;
    for (int i = t; i < nb; i += 256) hist[i] = 0;
    __syncthreads();
    const int stride = gridDim.x * 256;
    for (int e = blockIdx.x * 256 + t; e < E; e += stride)
        atomicAdd(&hist[ei[E + e] >> BSHIFT], 1);
    __syncthreads();
    for (int i = t; i < nb; i += 256)
        if (hist[i]) atomicAdd(gcnt + i, hist[i]);
}

__global__ __launch_bounds__(1024) void k_bscan(const int* __restrict__ gcnt,
                                                int* __restrict__ boff, int* __restrict__ bcur,
                                                int* __restrict__ row_ptr, int nb, int N) {
    __shared__ int sd[1024];
    int t = threadIdx.x;
    int own = (t < nb) ? gcnt[t] : 0;
    sd[t] = own;
    __syncthreads();
    #pragma unroll
    for (int off = 1; off < 1024; off <<= 1) {
        int v = (t >= off) ? sd[t - off] : 0;
        __syncthreads();
        sd[t] += v;
        __syncthreads();
    }
    if (t < nb) {
        boff[t + 1] = sd[t];
        bcur[t] = sd[t] - own;          // exclusive
        if (t == nb - 1) row_ptr[N] = sd[t];
    }
    if (t == 0) boff[0] = 0;
}

__global__ __launch_bounds__(256) void k_part(const int* __restrict__ ei, int E,
                                              int* __restrict__ bcur, int2* __restrict__ pedge,
                                              int nb) {
    __shared__ int hist[NBUCK_MAX];
    __shared__ int start[NBUCK_MAX];
    const int t = threadIdx.x;
    const int chunk = (E + gridDim.x - 1) / gridDim.x;
    const int c0 = blockIdx.x * chunk;
    const int c1 = min(c0 + chunk, E);
    for (int i = t; i < nb; i += 256) hist[i] = 0;
    __syncthreads();
    for (int e = c0 + t; e < c1; e += 256)
        atomicAdd(&hist[ei[E + e] >> BSHIFT], 1);
    __syncthreads();
    for (int i = t; i < nb; i += 256) {
        int h = hist[i];
        start[i] = h ? atomicAdd(bcur + i, h) : 0;
        hist[i] = 0;                     // reuse as local cursor
    }
    __syncthreads();
    for (int e = c0 + t; e < c1; e += 256) {
        int s = ei[e], d = ei[E + e];
        int b = d >> BSHIFT;
        int pos = start[b] + atomicAdd(&hist[b], 1);
        pedge[pos] = make_int2(s, d);
    }
}

__global__ __launch_bounds__(512) void k_bcsr(const int2* __restrict__ pedge,
                                              const int* __restrict__ boff,
                                              int* __restrict__ row_ptr, int* __restrict__ col,
                                              int N) {
    __shared__ int cnt[BSIZE];
    __shared__ int sc[BSIZE];
    __shared__ int cur[BSIZE];
    const int b  = blockIdx.x;
    const int t  = threadIdx.x;
    const int e0 = boff[b], e1 = boff[b + 1];
    const int base = b << BSHIFT;
    const int nv = min(BSIZE, N - base);
    cnt[t] = 0;
    __syncthreads();
    for (int e = e0 + t; e < e1; e += 512)
        atomicAdd(&cnt[pedge[e].y - base], 1);
    __syncthreads();
    sc[t] = cnt[t];
    __syncthreads();
    #pragma unroll
    for (int off = 1; off < BSIZE; off <<= 1) {
        int v = (t >= off) ? sc[t - off] : 0;
        __syncthreads();
        sc[t] += v;
        __syncthreads();
    }
    if (t < nv) {
        int excl = sc[t] - cnt[t];
        row_ptr[base + t] = e0 + excl;
        cur[t] = excl;
    }
    __syncthreads();
    for (int e = e0 + t; e < e1; e += 512) {
        int2 r = pedge[e];
        int d = r.y - base;
        int pos = e0 + atomicAdd(&cur[d], 1);
        col[pos] = r.x;
    }
}

// ---------------- layer-1: MFMA projection fused with pack ----------------

__global__ void k_convW(const float* __restrict__ W, unsigned short* __restrict__ WtG) {
    int id = blockIdx.x * blockDim.x + threadIdx.x;   // 112*256
    int n = id >> 8, k = id & 255;
    float v = (n < HC) ? W[k * HC + n] : 0.f;
    WtG[id] = (unsigned short)(__float_as_uint(v) >> 16);  // exact: inputs bf16-rounded
}

// LDS-free weights: B-fragments loaded directly from WtG (57 KB, L2/L3-hot)
// inside the unrolled MFMA loop. LDS holds only the 25.3 KB output transpose
// buffer -> ~6 blocks/CU instead of 2. One barrier total.
// xpack[n*H+h] = {7 msg fp16, src-logit*log2e fp16}; aldst = dst logit*log2e.
__global__ __launch_bounds__(256) void k_proj1_mfma(
    const float* __restrict__ x, const unsigned short* __restrict__ WtG,
    const float* __restrict__ asrc, const float* __restrict__ adst,
    uint4* __restrict__ xpack, float* __restrict__ aldst, int N)
{
    __shared__ float vals_s[64 * VS_STRIDE];               // 25344 B
    __shared__ float as_s[HC], ad_s[HC];
    const int t  = threadIdx.x;
    const int wv = t >> 6;
    const int l  = t & 63;
    const int ln = l & 15;
    const int qd = l >> 4;
    const int rowBase = blockIdx.x * 64;

    if (t < HC) { as_s[t] = asrc[t]; ad_s[t] = adst[t]; }

    // my MFMA A-row: rowBase + wv*16 + ln (clamped; pack loop guards gn >= N)
    int gr = rowBase + (wv << 4) + ln; if (gr >= N) gr = N - 1;
    const float* xr = x + (size_t)gr * FIN;

    // load all 8 steps' A-fragments: step s -> cols s*32 + qd*8 .. +7
    short8 afr[8];
    #pragma unroll
    for (int s = 0; s < 8; ++s) {
        float4 v0 = *(const float4*)(xr + s * 32 + qd * 8);
        float4 v1 = *(const float4*)(xr + s * 32 + qd * 8 + 4);
        short8 a;
        a[0] = (short)(__float_as_uint(v0.x) >> 16);
        a[1] = (short)(__float_as_uint(v0.y) >> 16);
        a[2] = (short)(__float_as_uint(v0.z) >> 16);
        a[3] = (short)(__float_as_uint(v0.w) >> 16);
        a[4] = (short)(__float_as_uint(v1.x) >> 16);
        a[5] = (short)(__float_as_uint(v1.y) >> 16);
        a[6] = (short)(__float_as_uint(v1.z) >> 16);
        a[7] = (short)(__float_as_uint(v1.w) >> 16);
        afr[s] = a;
    }

    // B-fragment base for (ln, qd): row ct*16+ln of WtG[112][256], cols s*32+qd*8
    const unsigned short* wb = WtG + ln * 256 + qd * 8;

    floatx4 acc[7] = {};
    #pragma unroll
    for (int s = 0; s < 8; ++s) {
        #pragma unroll
        for (int ct = 0; ct < 7; ++ct) {
            short8 b = *(const short8*)(wb + ct * (16 * 256) + s * 32);
            acc[ct] = __builtin_amdgcn_mfma_f32_16x16x32_bf16(afr[s], b, acc[ct], 0, 0, 0);
        }
    }

    // C/D: col = ln, row = qd*4 + r (local row = wv*16 + qd*4 + r); waves write
    // disjoint row ranges, so one barrier (before pack reads) suffices.
    #pragma unroll
    for (int ct = 0; ct < 7; ++ct) {
        int colg = ct * 16 + ln;
        if (colg < HC) {
            #pragma unroll
            for (int r = 0; r < 4; ++r)
                vals_s[((wv << 4) + (qd << 2) + r) * VS_STRIDE + colg] = acc[ct][r];
        }
    }
    __syncthreads();

    // pack: 64 nodes x 14 heads = 896 records
    for (int p = t; p < 64 * H; p += 256) {
        int nl = p / H, h = p - nl * H;
        int gn = rowBase + nl;
        if (gn >= N) break;
        const float* vp = vals_s + nl * VS_STRIDE + h * C;
        float v[C];
        float s1 = 0.f, s2 = 0.f;
        #pragma unroll
        for (int c2 = 0; c2 < C; ++c2) {
            float f = vp[c2];
            v[c2] = f;
            s1 = fmaf(f, as_s[h * C + c2], s1);
            s2 = fmaf(f, ad_s[h * C + c2], s2);
        }
        uint4 pk;
        pk.x = hpk(v[0], v[1]);
        pk.y = hpk(v[2], v[3]);
        pk.z = hpk(v[4], v[5]);
        pk.w = hpk(v[6], s1 * LOG2E);
        xpack[(size_t)gn * H + h] = pk;
        aldst[(size_t)gn * H + h] = s2 * LOG2E;
    }
}

// ---------------- layer-2 projection + pack (thread per node) ----------------

__global__ __launch_bounds__(256) void k_proj2_pack(
    const float* __restrict__ h1, const float* __restrict__ W,
    const float* __restrict__ asrc, const float* __restrict__ adst,
    uint4* __restrict__ xpack, float* __restrict__ aldst, int N)
{
    __shared__ float Ws[C * HC];
    __shared__ float as_s[HC], ad_s[HC];
    const int t = threadIdx.x;
    for (int i = t; i < C * HC; i += 256) Ws[i] = W[i];
    if (t < HC) { as_s[t] = asrc[t]; ad_s[t] = adst[t]; }
    __syncthreads();
    int n = blockIdx.x * 256 + t;
    if (n >= N) return;
    float xr[C];
    #pragma unroll
    for (int c2 = 0; c2 < C; ++c2) xr[c2] = h1[(size_t)n * C + c2];
    #pragma unroll
    for (int h = 0; h < H; ++h) {
        float v[C], s1 = 0.f, s2 = 0.f;
        #pragma unroll
        for (int c2 = 0; c2 < C; ++c2) {
            float acc = 0.f;
            #pragma unroll
            for (int k = 0; k < C; ++k)
                acc = fmaf(xr[k], Ws[k * HC + h * C + c2], acc);
            v[c2] = acc;
            s1 = fmaf(acc, as_s[h * C + c2], s1);
            s2 = fmaf(acc, ad_s[h * C + c2], s2);
        }
        uint4 pk;
        pk.x = hpk(v[0], v[1]);
        pk.y = hpk(v[2], v[3]);
        pk.z = hpk(v[4], v[5]);
        pk.w = hpk(v[6], s1 * LOG2E);
        xpack[(size_t)n * H + h] = pk;     // 224 B contiguous per thread
        aldst[(size_t)n * H + h] = s2 * LOG2E;
    }
}

// ---------------- fused aggregation: ONE WAVE PER NODE ----------------
// lane = e4*16 + h: e4 in 0..3 = edge slot, h in 0..15 = head (h<14 active).
// Fixed shift K = leaky(ld+2) makes softmax state LINEAR: partial den sums
// and partial channel-maxes combine across edge slots via shfl_xor(16,32);
// head-mean then reduces via shfl_xor(1,2,4,8). No LDS, no __syncthreads.
// col[] is padded by 64 zeroed ints past E, so prefetch needs no clamping.
#define AGG_STEP(DEN, REC)                                              \
    {                                                                   \
        float l = hhi((REC).w) + ld;                                    \
        float p = __builtin_amdgcn_exp2f(fmaxf(l, 0.2f * l) - K);       \
        DEN += p;                                                       \
        _Float16 ph = (_Float16)p;                                      \
        h2 p2 = { ph, ph };                                             \
        m0 = __builtin_elementwise_max(m0, p2 * u2h((REC).x));          \
        m1 = __builtin_elementwise_max(m1, p2 * u2h((REC).y));          \
        m2 = __builtin_elementwise_max(m2, p2 * u2h((REC).z));          \
        m3 = __builtin_elementwise_max(m3, p2 * u2h((REC).w));          \
    }

template<int LAYER>
__global__ __launch_bounds__(256) void k_agg(
    const int* __restrict__ row_ptr, const int* __restrict__ col,
    const uint4* __restrict__ xpack, const float* __restrict__ aldst,
    const float* __restrict__ bias,
    float* __restrict__ h1, float* __restrict__ out, int N)
{
    const int t    = threadIdx.x;
    const int lane = t & 63;
    const int e4   = lane >> 4;          // edge slot 0..3
    const int h    = lane & 15;          // head slot (active if < 14)
    const int n    = blockIdx.x * 4 + (t >> 6);
    const bool act = (h < H) && (n < N);

    float den = 0.f, den2 = 0.f;
    h2 m0 = u2h(0xFC00FC00u), m1 = m0, m2 = m0, m3 = m0;   // -inf packed
    float ld = 0.f, K = 0.f;

    if (act) {
        const int e0  = row_ptr[n];
        const int deg = row_ptr[n + 1] - e0;
        ld = aldst[(unsigned)n * H + h];                   // already * log2e
        float kb = ld + 2.0f * LOG2E;
        K = fmaxf(kb, 0.2f * kb);                          // leaky(ld+2), log2 domain

        if (e4 == 0) {                                     // implicit self loop (once)
            uint4 pk = xpack[(unsigned)n * H + h];
            float l = hhi(pk.w) + ld;
            float p = __builtin_amdgcn_exp2f(fmaxf(l, 0.2f * l) - K);
            den = p;
            _Float16 ph = (_Float16)p;
            h2 p2 = { ph, ph };
            m0 = p2 * u2h(pk.x);
            m1 = p2 * u2h(pk.y);
            m2 = p2 * u2h(pk.z);
            m3 = p2 * u2h(pk.w);                           // hi half ignored later
        }

        if (deg > 0) {
            const int* cp = col + e0;
            int i = e4;                                    // edges i = e4 + 4k
            int c0 = cp[i];
            int c1 = cp[i + 4];
            uint4 r0 = xpack[(unsigned)c0 * H + h];
            uint4 r1 = xpack[(unsigned)c1 * H + h];
            c0 = cp[i + 8];
            c1 = cp[i + 12];
            for (; i < deg; i += 8) {
                uint4 curA = r0, curB = r1;
                r0 = xpack[(unsigned)c0 * H + h];
                r1 = xpack[(unsigned)c1 * H + h];
                c0 = cp[i + 16];
                c1 = cp[i + 20];
                AGG_STEP(den,  curA);                      // edge i
                if (i + 4 < deg) AGG_STEP(den2, curB);     // edge i+4
            }
        }
    }
    den += den2;

    // ---- combine across edge slots (lanes h, h+16, h+32, h+48) ----
    den += __shfl_xor(den, 16, 64);
    den += __shfl_xor(den, 32, 64);
    m0 = hshfl_max(m0, 16); m0 = hshfl_max(m0, 32);
    m1 = hshfl_max(m1, 16); m1 = hshfl_max(m1, 32);
    m2 = hshfl_max(m2, 16); m2 = hshfl_max(m2, 32);
    m3 = hshfl_max(m3, 16); m3 = hshfl_max(m3, 32);

    float v[C];
    if (act) {
        float rd = 1.f / den;                              // den >= p_self > 0
        v[0] = (float)m0.x * rd; v[1] = (float)m0.y * rd;
        v[2] = (float)m1.x * rd; v[3] = (float)m1.y * rd;
        v[4] = (float)m2.x * rd; v[5] = (float)m2.y * rd;
        v[6] = (float)m3.x * rd;
    } else {
        #pragma unroll
        for (int c = 0; c < C; ++c) v[c] = 0.f;
    }

    // ---- head mean across 16-lane group ----
    #pragma unroll
    for (int off = 1; off <= 8; off <<= 1) {
        #pragma unroll
        for (int c = 0; c < C; ++c) v[c] += __shfl_xor(v[c], off, 64);
    }

    if (n >= N) return;
    if (LAYER == 1) {
        if (lane < C) {
            float myv = v[0];
            #pragma unroll
            for (int c = 1; c < C; ++c) if (lane == c) myv = v[c];
            h1[(size_t)n * C + lane] = fmaxf(myv * (1.f / H) + bias[lane], 0.f);
        }
    } else {
        float o[C];
        #pragma unroll
        for (int c = 0; c < C; ++c) o[c] = v[c] * (1.f / H) + bias[c];
        float mv = o[0];
        #pragma unroll
        for (int c = 1; c < C; ++c) mv = fmaxf(mv, o[c]);
        float lse = 0.f;
        #pragma unroll
        for (int c = 0; c < C; ++c) lse += __expf(o[c] - mv);
        lse = logf(lse);
        if (lane < C) {
            float myo = o[0];
            #pragma unroll
            for (int c = 1; c < C; ++c) if (lane == c) myo = o[c];
            out[(size_t)n * C + lane] = myo - mv - lse;
        }
    }
}

// ---------------- launch ----------------

static inline size_t align16(size_t v) { return (v + 15) & ~(size_t)15; }

extern "C" void kernel_launch(void* const* d_in, const int* in_sizes, int n_in,
                              void* d_out, int out_size, void* d_ws, size_t ws_size,
                              hipStream_t stream)
{
    const float* x     = (const float*)d_in[0];
    const int*   ei    = (const int*)d_in[1];
    const float* W1    = (const float*)d_in[2];
    const float* asrc1 = (const float*)d_in[3];
    const float* adst1 = (const float*)d_in[4];
    const float* b1    = (const float*)d_in[5];
    const float* W2    = (const float*)d_in[6];
    const float* asrc2 = (const float*)d_in[7];
    const float* adst2 = (const float*)d_in[8];
    const float* b2    = (const float*)d_in[9];

    const int N  = in_sizes[0] / FIN;   // 100000
    const int E  = in_sizes[1] / 2;     // 1600000
    const int nb = (N + BSIZE - 1) >> BSHIFT;   // 196

    char* w = (char*)d_ws;
    uint4* xpack   = (uint4*)w; w += align16((size_t)N * H * 16);   // 22.4 MB
    int2*  pedge   = (int2*)w;  w += align16((size_t)E * 8);        // 12.8 MB
    float* aldst   = (float*)w; w += align16((size_t)N * H * 4);    //  5.6 MB
    float* h1      = (float*)w; w += align16((size_t)N * C * 4);    //  2.8 MB
    int*   row_ptr = (int*)w;   w += align16((size_t)(N + 1) * 4);
    int*   col     = (int*)w;   w += align16((size_t)(E + 64) * 4); //  6.4 MB + pad
    int*   gcnt    = (int*)w;   w += align16((size_t)nb * 4);
    int*   boff    = (int*)w;   w += align16((size_t)(nb + 1) * 4);
    int*   bcur    = (int*)w;   w += align16((size_t)nb * 4);
    unsigned short* WtG = (unsigned short*)w; w += align16((size_t)WT_ROWS * FIN * 2);

    const int gAgg  = (N + 3) / 4;      // one wave per node, 4 waves/block
    const int gMfma = (N + 63) / 64;
    const int g256N = (N + 255) / 256;

    // ---- bucketed CSR build (no self loops; rebuilt every call) ----
    k_zero2<<<1, 256, 0, stream>>>(gcnt, nb, col + E, 64);
    k_hist<<<256, 256, 0, stream>>>(ei, E, gcnt, nb);
    k_bscan<<<1, 1024, 0, stream>>>(gcnt, boff, bcur, row_ptr, nb, N);
    k_part<<<256, 256, 0, stream>>>(ei, E, bcur, pedge, nb);
    k_bcsr<<<nb, 512, 0, stream>>>(pedge, boff, row_ptr, col, N);

    // ---- layer 1 ----
    k_convW<<<(WT_ROWS * FIN + 255) / 256, 256, 0, stream>>>(W1, WtG);
    k_proj1_mfma<<<gMfma, 256, 0, stream>>>(x, WtG, asrc1, adst1, xpack, aldst, N);
    k_agg<1><<<gAgg, 256, 0, stream>>>(row_ptr, col, xpack, aldst, b1,
                                       h1, (float*)d_out, N);
    // ---- layer 2 ----
    k_proj2_pack<<<g256N, 256, 0, stream>>>(h1, W2, asrc2, adst2, xpack, aldst, N);
    k_agg<2><<<gAgg, 256, 0, stream>>>(row_ptr, col, xpack, aldst, b2,
                                       h1, (float*)d_out, N);
}

// Round 9
// 423.649 us; speedup vs baseline: 1.1947x; 1.0791x over previous
//
#include <hip/hip_runtime.h>
#include <math.h>

#define H  14
#define C  7
#define HC 98
#define FIN 256
#define NEG_SLOPE 0.2f
#define LOG2E 1.44269504088896f

#define BSHIFT 9
#define BSIZE  512
#define NBUCK_MAX 256

typedef __attribute__((ext_vector_type(8))) short short8;
typedef __attribute__((ext_vector_type(4))) float floatx4;
typedef _Float16 h2 __attribute__((ext_vector_type(2)));

#define WT_ROWS   112            // 98 cols zero-padded to 7*16
#define WT_STRIDE 264            // 256 + 8 pad (bf16 units)
#define VS_STRIDE 99             // 98 + 1 pad (f32 units)

// ---- fp16 helpers via native _Float16 vectors (no hip_fp16.h dependence) ----
__device__ __forceinline__ h2 u2h(unsigned u) { return __builtin_bit_cast(h2, u); }
__device__ __forceinline__ unsigned hpk(float a, float b) {
    h2 v = { (_Float16)a, (_Float16)b };
    return __builtin_bit_cast(unsigned, v);
}
__device__ __forceinline__ float hhi(unsigned w) {
    unsigned short s = (unsigned short)(w >> 16);
    return (float)__builtin_bit_cast(_Float16, s);
}
// max-combine of packed fp16 pair across lanes (xor mask)
__device__ __forceinline__ h2 hshfl_max(h2 v, int mask) {
    int u = __builtin_bit_cast(int, v);
    int o = __shfl_xor(u, mask, 64);
    return __builtin_elementwise_max(v, u2h((unsigned)o));
}

// ---------------- bucketed CSR construction (no self loops) ----------------

__global__ void k_zero2(int* __restrict__ a, int na, int* __restrict__ b, int nbb) {
    int i = blockIdx.x * blockDim.x + threadIdx.x;
    if (i < na) a[i] = 0;
    if (i < nbb) b[i] = 0;
}

__global__ __launch_bounds__(256) void k_hist(const int* __restrict__ ei, int E,
                                              int* __restrict__ gcnt, int nb) {
    __shared__ int hist[NBUCK_MAX];
    const int t = threadIdx.x;
    for (int i = t; i < nb; i += 256) hist[i] = 0;
    __syncthreads();
    const int stride = gridDim.x * 256;
    for (int e = blockIdx.x * 256 + t; e < E; e += stride)
        atomicAdd(&hist[ei[E + e] >> BSHIFT], 1);
    __syncthreads();
    for (int i = t; i < nb; i += 256)
        if (hist[i]) atomicAdd(gcnt + i, hist[i]);
}

__global__ __launch_bounds__(1024) void k_bscan(const int* __restrict__ gcnt,
                                                int* __restrict__ boff, int* __restrict__ bcur,
                                                int* __restrict__ row_ptr, int nb, int N) {
    __shared__ int sd[1024];
    int t = threadIdx.x;
    int own = (t < nb) ? gcnt[t] : 0;
    sd[t] = own;
    __syncthreads();
    #pragma unroll
    for (int off = 1; off < 1024; off <<= 1) {
        int v = (t >= off) ? sd[t - off] : 0;
        __syncthreads();
        sd[t] += v;
        __syncthreads();
    }
    if (t < nb) {
        boff[t + 1] = sd[t];
        bcur[t] = sd[t] - own;          // exclusive
        if (t == nb - 1) row_ptr[N] = sd[t];
    }
    if (t == 0) boff[0] = 0;
}

__global__ __launch_bounds__(256) void k_part(const int* __restrict__ ei, int E,
                                              int* __restrict__ bcur, int2* __restrict__ pedge,
                                              int nb) {
    __shared__ int hist[NBUCK_MAX];
    __shared__ int start[NBUCK_MAX];
    const int t = threadIdx.x;
    const int chunk = (E + gridDim.x - 1) / gridDim.x;
    const int c0 = blockIdx.x * chunk;
    const int c1 = min(c0 + chunk, E);
    for (int i = t; i < nb; i += 256) hist[i] = 0;
    __syncthreads();
    for (int e = c0 + t; e < c1; e += 256)
        atomicAdd(&hist[ei[E + e] >> BSHIFT], 1);
    __syncthreads();
    for (int i = t; i < nb; i += 256) {
        int h = hist[i];
        start[i] = h ? atomicAdd(bcur + i, h) : 0;
        hist[i] = 0;                     // reuse as local cursor
    }
    __syncthreads();
    for (int e = c0 + t; e < c1; e += 256) {
        int s = ei[e], d = ei[E + e];
        int b = d >> BSHIFT;
        int pos = start[b] + atomicAdd(&hist[b], 1);
        pedge[pos] = make_int2(s, d);
    }
}

__global__ __launch_bounds__(512) void k_bcsr(const int2* __restrict__ pedge,
                                              const int* __restrict__ boff,
                                              int* __restrict__ row_ptr, int* __restrict__ col,
                                              int N) {
    __shared__ int cnt[BSIZE];
    __shared__ int sc[BSIZE];
    __shared__ int cur[BSIZE];
    const int b  = blockIdx.x;
    const int t  = threadIdx.x;
    const int e0 = boff[b], e1 = boff[b + 1];
    const int base = b << BSHIFT;
    const int nv = min(BSIZE, N - base);
    cnt[t] = 0;
    __syncthreads();
    for (int e = e0 + t; e < e1; e += 512)
        atomicAdd(&cnt[pedge[e].y - base], 1);
    __syncthreads();
    sc[t] = cnt[t];
    __syncthreads();
    #pragma unroll
    for (int off = 1; off < BSIZE; off <<= 1) {
        int v = (t >= off) ? sc[t - off] : 0;
        __syncthreads();
        sc[t] += v;
        __syncthreads();
    }
    if (t < nv) {
        int excl = sc[t] - cnt[t];
        row_ptr[base + t] = e0 + excl;
        cur[t] = excl;
    }
    __syncthreads();
    for (int e = e0 + t; e < e1; e += 512) {
        int2 r = pedge[e];
        int d = r.y - base;
        int pos = e0 + atomicAdd(&cur[d], 1);
        col[pos] = r.x;
    }
}

// ---------------- layer-1: MFMA projection fused with pack ----------------

__global__ void k_convW(const float* __restrict__ W, unsigned short* __restrict__ WtG) {
    int id = blockIdx.x * blockDim.x + threadIdx.x;   // 112*256
    int n = id >> 8, k = id & 255;
    float v = (n < HC) ? W[k * HC + n] : 0.f;
    WtG[id] = (unsigned short)(__float_as_uint(v) >> 16);  // exact: inputs bf16-rounded
}

// Barrier-free K-loop: A-fragments loaded global->reg per lane (no x staging,
// no per-step barriers). Weights staged once in LDS; LDS reused for the
// output transpose after the K-loop. (Best measured variant; direct-global
// weights regressed — r8: 56 serial L2 loads per wave at 52 VGPRs.)
__global__ __launch_bounds__(256) void k_proj1_mfma(
    const float* __restrict__ x, const unsigned short* __restrict__ WtG,
    const float* __restrict__ asrc, const float* __restrict__ adst,
    uint4* __restrict__ xpack, float* __restrict__ aldst, int N)
{
    __shared__ unsigned short wt_s[WT_ROWS * WT_STRIDE];  // 59136 B (reused as f32 vals)
    __shared__ float as_s[HC], ad_s[HC];
    float* vals_s = (float*)wt_s;                          // 64*99*4 = 25344 B < 59136
    const int t  = threadIdx.x;
    const int wv = t >> 6;
    const int l  = t & 63;
    const int ln = l & 15;
    const int qd = l >> 4;
    const int rowBase = blockIdx.x * 64;

    #pragma unroll
    for (int i = 0; i < 14; ++i) {
        int f = i * 256 + t;            // uint4 index, 3584 total (32 per row)
        int r = f >> 5, pos = f & 31;
        *(uint4*)(wt_s + r * WT_STRIDE + pos * 8) = ((const uint4*)WtG)[f];
    }
    if (t < HC) { as_s[t] = asrc[t]; ad_s[t] = adst[t]; }
    __syncthreads();

    // my MFMA A-row: rowBase + wv*16 + ln (clamped; pack loop guards gn >= N)
    int gr = rowBase + (wv << 4) + ln; if (gr >= N) gr = N - 1;
    const float* xr = x + (size_t)gr * FIN;

    // load all 8 steps' A-fragments: step s -> cols s*32 + qd*8 .. +7
    short8 afr[8];
    #pragma unroll
    for (int s = 0; s < 8; ++s) {
        float4 v0 = *(const float4*)(xr + s * 32 + qd * 8);
        float4 v1 = *(const float4*)(xr + s * 32 + qd * 8 + 4);
        short8 a;
        a[0] = (short)(__float_as_uint(v0.x) >> 16);
        a[1] = (short)(__float_as_uint(v0.y) >> 16);
        a[2] = (short)(__float_as_uint(v0.z) >> 16);
        a[3] = (short)(__float_as_uint(v0.w) >> 16);
        a[4] = (short)(__float_as_uint(v1.x) >> 16);
        a[5] = (short)(__float_as_uint(v1.y) >> 16);
        a[6] = (short)(__float_as_uint(v1.z) >> 16);
        a[7] = (short)(__float_as_uint(v1.w) >> 16);
        afr[s] = a;
    }

    floatx4 acc[7] = {};
    #pragma unroll
    for (int s = 0; s < 8; ++s) {
        const int k0 = s * 32;
        #pragma unroll
        for (int ct = 0; ct < 7; ++ct) {
            short8 b = *(const short8*)(wt_s + (ct * 16 + ln) * WT_STRIDE + k0 + qd * 8);
            acc[ct] = __builtin_amdgcn_mfma_f32_16x16x32_bf16(afr[s], b, acc[ct], 0, 0, 0);
        }
    }

    __syncthreads();                    // all waves done with wt_s; reuse as vals_s
    // C/D: col = ln, row = qd*4 + r (local row = wv*16 + qd*4 + r)
    #pragma unroll
    for (int ct = 0; ct < 7; ++ct) {
        int colg = ct * 16 + ln;
        if (colg < HC) {
            #pragma unroll
            for (int r = 0; r < 4; ++r)
                vals_s[((wv << 4) + (qd << 2) + r) * VS_STRIDE + colg] = acc[ct][r];
        }
    }
    __syncthreads();

    // pack: 64 nodes x 14 heads = 896 records (consecutive t -> consecutive
    // 16 B records -> coalesced xpack writes)
    for (int p = t; p < 64 * H; p += 256) {
        int nl = p / H, h = p - nl * H;
        int gn = rowBase + nl;
        if (gn >= N) break;
        const float* vp = vals_s + nl * VS_STRIDE + h * C;
        float v[C];
        float s1 = 0.f, s2 = 0.f;
        #pragma unroll
        for (int c2 = 0; c2 < C; ++c2) {
            float f = vp[c2];
            v[c2] = f;
            s1 = fmaf(f, as_s[h * C + c2], s1);
            s2 = fmaf(f, ad_s[h * C + c2], s2);
        }
        uint4 pk;
        pk.x = hpk(v[0], v[1]);
        pk.y = hpk(v[2], v[3]);
        pk.z = hpk(v[4], v[5]);
        pk.w = hpk(v[6], s1 * LOG2E);
        xpack[(size_t)gn * H + h] = pk;
        aldst[(size_t)gn * H + h] = s2 * LOG2E;
    }
}

// ---------------- layer-2 projection + pack: LDS-staged coalesced output ----
// Old version: each thread wrote 14x16B at stride 224B -> every store touched
// 64 distinct lines (4x write amplification, ~65 us). Now: stage 256 nodes'
// records node-major in LDS (57 KB), flush with consecutive-thread-consecutive-
// uint4 coalesced writes; reuse the LDS region for the aldst flush.

__global__ __launch_bounds__(256) void k_proj2_pack(
    const float* __restrict__ h1, const float* __restrict__ W,
    const float* __restrict__ asrc, const float* __restrict__ adst,
    uint4* __restrict__ xpack, float* __restrict__ aldst, int N)
{
    __shared__ uint4 opk[256 * H];      // 57344 B (reused as float for aldst)
    __shared__ float Ws[C * HC];
    __shared__ float as_s[HC], ad_s[HC];
    const int t = threadIdx.x;
    for (int i = t; i < C * HC; i += 256) Ws[i] = W[i];
    if (t < HC) { as_s[t] = asrc[t]; ad_s[t] = adst[t]; }
    __syncthreads();

    const int nbase = blockIdx.x * 256;
    const int nv = min(256, N - nbase);          // live nodes in this block
    const int n = nbase + t;
    float s2r[H];

    if (t < nv) {
        float xr[C];
        #pragma unroll
        for (int c2 = 0; c2 < C; ++c2) xr[c2] = h1[(size_t)n * C + c2];
        #pragma unroll
        for (int h = 0; h < H; ++h) {
            float v[C], s1 = 0.f, s2 = 0.f;
            #pragma unroll
            for (int c2 = 0; c2 < C; ++c2) {
                float acc = 0.f;
                #pragma unroll
                for (int k = 0; k < C; ++k)
                    acc = fmaf(xr[k], Ws[k * HC + h * C + c2], acc);
                v[c2] = acc;
                s1 = fmaf(acc, as_s[h * C + c2], s1);
                s2 = fmaf(acc, ad_s[h * C + c2], s2);
            }
            uint4 pk;
            pk.x = hpk(v[0], v[1]);
            pk.y = hpk(v[2], v[3]);
            pk.z = hpk(v[4], v[5]);
            pk.w = hpk(v[6], s1 * LOG2E);
            opk[t * H + h] = pk;
            s2r[h] = s2 * LOG2E;
        }
    }
    __syncthreads();

    // flush xpack: nv*14 records, coalesced
    {
        uint4* dst = xpack + (size_t)nbase * H;
        const int tot = nv * H;
        for (int i = t; i < tot; i += 256) dst[i] = opk[i];
    }
    __syncthreads();

    // reuse opk region for aldst staging
    float* oal = (float*)opk;
    if (t < nv) {
        #pragma unroll
        for (int h = 0; h < H; ++h) oal[t * H + h] = s2r[h];
    }
    __syncthreads();
    {
        float* dst = aldst + (size_t)nbase * H;
        const int tot = nv * H;
        for (int i = t; i < tot; i += 256) dst[i] = oal[i];
    }
}

// ---------------- fused aggregation: ONE WAVE PER NODE ----------------
// lane = e4*16 + h: e4 in 0..3 = edge slot, h in 0..15 = head (h<14 active).
// Fixed shift K = leaky(ld+2) makes softmax state LINEAR: partial den sums
// and partial channel-maxes combine across edge slots via shfl_xor(16,32);
// head-mean then reduces via shfl_xor(1,2,4,8). No LDS, no __syncthreads.
// col[] is padded by 64 zeroed ints past E, so prefetch needs no clamping.
#define AGG_STEP(DEN, REC)                                              \
    {                                                                   \
        float l = hhi((REC).w) + ld;                                    \
        float p = __builtin_amdgcn_exp2f(fmaxf(l, 0.2f * l) - K);       \
        DEN += p;                                                       \
        _Float16 ph = (_Float16)p;                                      \
        h2 p2 = { ph, ph };                                             \
        m0 = __builtin_elementwise_max(m0, p2 * u2h((REC).x));          \
        m1 = __builtin_elementwise_max(m1, p2 * u2h((REC).y));          \
        m2 = __builtin_elementwise_max(m2, p2 * u2h((REC).z));          \
        m3 = __builtin_elementwise_max(m3, p2 * u2h((REC).w));          \
    }

template<int LAYER>
__global__ __launch_bounds__(256) void k_agg(
    const int* __restrict__ row_ptr, const int* __restrict__ col,
    const uint4* __restrict__ xpack, const float* __restrict__ aldst,
    const float* __restrict__ bias,
    float* __restrict__ h1, float* __restrict__ out, int N)
{
    const int t    = threadIdx.x;
    const int lane = t & 63;
    const int e4   = lane >> 4;          // edge slot 0..3
    const int h    = lane & 15;          // head slot (active if < 14)
    const int n    = blockIdx.x * 4 + (t >> 6);
    const bool act = (h < H) && (n < N);

    float den = 0.f, den2 = 0.f;
    h2 m0 = u2h(0xFC00FC00u), m1 = m0, m2 = m0, m3 = m0;   // -inf packed
    float ld = 0.f, K = 0.f;

    if (act) {
        const int e0  = row_ptr[n];
        const int deg = row_ptr[n + 1] - e0;
        ld = aldst[(unsigned)n * H + h];                   // already * log2e
        float kb = ld + 2.0f * LOG2E;
        K = fmaxf(kb, 0.2f * kb);                          // leaky(ld+2), log2 domain

        if (e4 == 0) {                                     // implicit self loop (once)
            uint4 pk = xpack[(unsigned)n * H + h];
            float l = hhi(pk.w) + ld;
            float p = __builtin_amdgcn_exp2f(fmaxf(l, 0.2f * l) - K);
            den = p;
            _Float16 ph = (_Float16)p;
            h2 p2 = { ph, ph };
            m0 = p2 * u2h(pk.x);
            m1 = p2 * u2h(pk.y);
            m2 = p2 * u2h(pk.z);
            m3 = p2 * u2h(pk.w);                           // hi half ignored later
        }

        if (deg > 0) {
            const int* cp = col + e0;
            int i = e4;                                    // edges i = e4 + 4k
            int c0 = cp[i];
            int c1 = cp[i + 4];
            uint4 r0 = xpack[(unsigned)c0 * H + h];
            uint4 r1 = xpack[(unsigned)c1 * H + h];
            c0 = cp[i + 8];
            c1 = cp[i + 12];
            for (; i < deg; i += 8) {
                uint4 curA = r0, curB = r1;
                r0 = xpack[(unsigned)c0 * H + h];
                r1 = xpack[(unsigned)c1 * H + h];
                c0 = cp[i + 16];
                c1 = cp[i + 20];
                AGG_STEP(den,  curA);                      // edge i
                if (i + 4 < deg) AGG_STEP(den2, curB);     // edge i+4
            }
        }
    }
    den += den2;

    // ---- combine across edge slots (lanes h, h+16, h+32, h+48) ----
    den += __shfl_xor(den, 16, 64);
    den += __shfl_xor(den, 32, 64);
    m0 = hshfl_max(m0, 16); m0 = hshfl_max(m0, 32);
    m1 = hshfl_max(m1, 16); m1 = hshfl_max(m1, 32);
    m2 = hshfl_max(m2, 16); m2 = hshfl_max(m2, 32);
    m3 = hshfl_max(m3, 16); m3 = hshfl_max(m3, 32);

    float v[C];
    if (act) {
        float rd = 1.f / den;                              // den >= p_self > 0
        v[0] = (float)m0.x * rd; v[1] = (float)m0.y * rd;
        v[2] = (float)m1.x * rd; v[3] = (float)m1.y * rd;
        v[4] = (float)m2.x * rd; v[5] = (float)m2.y * rd;
        v[6] = (float)m3.x * rd;
    } else {
        #pragma unroll
        for (int c = 0; c < C; ++c) v[c] = 0.f;
    }

    // ---- head mean across 16-lane group ----
    #pragma unroll
    for (int off = 1; off <= 8; off <<= 1) {
        #pragma unroll
        for (int c = 0; c < C; ++c) v[c] += __shfl_xor(v[c], off, 64);
    }

    if (n >= N) return;
    if (LAYER == 1) {
        if (lane < C) {
            float myv = v[0];
            #pragma unroll
            for (int c = 1; c < C; ++c) if (lane == c) myv = v[c];
            h1[(size_t)n * C + lane] = fmaxf(myv * (1.f / H) + bias[lane], 0.f);
        }
    } else {
        float o[C];
        #pragma unroll
        for (int c = 0; c < C; ++c) o[c] = v[c] * (1.f / H) + bias[c];
        float mv = o[0];
        #pragma unroll
        for (int c = 1; c < C; ++c) mv = fmaxf(mv, o[c]);
        float lse = 0.f;
        #pragma unroll
        for (int c = 0; c < C; ++c) lse += __expf(o[c] - mv);
        lse = logf(lse);
        if (lane < C) {
            float myo = o[0];
            #pragma unroll
            for (int c = 1; c < C; ++c) if (lane == c) myo = o[c];
            out[(size_t)n * C + lane] = myo - mv - lse;
        }
    }
}

// ---------------- launch ----------------

static inline size_t align16(size_t v) { return (v + 15) & ~(size_t)15; }

extern "C" void kernel_launch(void* const* d_in, const int* in_sizes, int n_in,
                              void* d_out, int out_size, void* d_ws, size_t ws_size,
                              hipStream_t stream)
{
    const float* x     = (const float*)d_in[0];
    const int*   ei    = (const int*)d_in[1];
    const float* W1    = (const float*)d_in[2];
    const float* asrc1 = (const float*)d_in[3];
    const float* adst1 = (const float*)d_in[4];
    const float* b1    = (const float*)d_in[5];
    const float* W2    = (const float*)d_in[6];
    const float* asrc2 = (const float*)d_in[7];
    const float* adst2 = (const float*)d_in[8];
    const float* b2    = (const float*)d_in[9];

    const int N  = in_sizes[0] / FIN;   // 100000
    const int E  = in_sizes[1] / 2;     // 1600000
    const int nb = (N + BSIZE - 1) >> BSHIFT;   // 196

    char* w = (char*)d_ws;
    uint4* xpack   = (uint4*)w; w += align16((size_t)N * H * 16);   // 22.4 MB
    int2*  pedge   = (int2*)w;  w += align16((size_t)E * 8);        // 12.8 MB
    float* aldst   = (float*)w; w += align16((size_t)N * H * 4);    //  5.6 MB
    float* h1      = (float*)w; w += align16((size_t)N * C * 4);    //  2.8 MB
    int*   row_ptr = (int*)w;   w += align16((size_t)(N + 1) * 4);
    int*   col     = (int*)w;   w += align16((size_t)(E + 64) * 4); //  6.4 MB + pad
    int*   gcnt    = (int*)w;   w += align16((size_t)nb * 4);
    int*   boff    = (int*)w;   w += align16((size_t)(nb + 1) * 4);
    int*   bcur    = (int*)w;   w += align16((size_t)nb * 4);
    unsigned short* WtG = (unsigned short*)w; w += align16((size_t)WT_ROWS * FIN * 2);

    const int gAgg  = (N + 3) / 4;      // one wave per node, 4 waves/block
    const int gMfma = (N + 63) / 64;
    const int g256N = (N + 255) / 256;

    // ---- bucketed CSR build (no self loops; rebuilt every call) ----
    k_zero2<<<1, 256, 0, stream>>>(gcnt, nb, col + E, 64);
    k_hist<<<256, 256, 0, stream>>>(ei, E, gcnt, nb);
    k_bscan<<<1, 1024, 0, stream>>>(gcnt, boff, bcur, row_ptr, nb, N);
    k_part<<<256, 256, 0, stream>>>(ei, E, bcur, pedge, nb);
    k_bcsr<<<nb, 512, 0, stream>>>(pedge, boff, row_ptr, col, N);

    // ---- layer 1 ----
    k_convW<<<(WT_ROWS * FIN + 255) / 256, 256, 0, stream>>>(W1, WtG);
    k_proj1_mfma<<<gMfma, 256, 0, stream>>>(x, WtG, asrc1, adst1, xpack, aldst, N);
    k_agg<1><<<gAgg, 256, 0, stream>>>(row_ptr, col, xpack, aldst, b1,
                                       h1, (float*)d_out, N);
    // ---- layer 2 ----
    k_proj2_pack<<<g256N, 256, 0, stream>>>(h1, W2, asrc2, adst2, xpack, aldst, N);
    k_agg<2><<<gAgg, 256, 0, stream>>>(row_ptr, col, xpack, aldst, b2,
                                       h1, (float*)d_out, N);
}

// Round 10
// 409.459 us; speedup vs baseline: 1.2361x; 1.0347x over previous
//
#include <hip/hip_runtime.h>
#include <math.h>

#define H  14
#define C  7
#define HC 98
#define FIN 256
#define NEG_SLOPE 0.2f
#define LOG2E 1.44269504088896f

#define BSHIFT 9
#define BSIZE  512
#define NBUCK_MAX 256

typedef __attribute__((ext_vector_type(8))) short short8;
typedef __attribute__((ext_vector_type(4))) float floatx4;
typedef _Float16 h2 __attribute__((ext_vector_type(2)));

#define WT_ROWS   112            // 98 cols zero-padded to 7*16
#define WT_STRIDE 264            // 256 + 8 pad (bf16 units)
#define VS_STRIDE 99             // 98 + 1 pad (f32 units)
#define P2NODES   128            // proj2 nodes per block

// ---- fp16 helpers via native _Float16 vectors (no hip_fp16.h dependence) ----
__device__ __forceinline__ h2 u2h(unsigned u) { return __builtin_bit_cast(h2, u); }
__device__ __forceinline__ unsigned hpk(float a, float b) {
    h2 v = { (_Float16)a, (_Float16)b };
    return __builtin_bit_cast(unsigned, v);
}
__device__ __forceinline__ float hhi(unsigned w) {
    unsigned short s = (unsigned short)(w >> 16);
    return (float)__builtin_bit_cast(_Float16, s);
}
// max-combine of packed fp16 pair across lanes (xor mask)
__device__ __forceinline__ h2 hshfl_max(h2 v, int mask) {
    int u = __builtin_bit_cast(int, v);
    int o = __shfl_xor(u, mask, 64);
    return __builtin_elementwise_max(v, u2h((unsigned)o));
}

// ---------------- fused prep: convW (blocks 0..111) + gcnt zero (block 112) ----

__global__ __launch_bounds__(256) void k_prep(const float* __restrict__ W,
                                              unsigned short* __restrict__ WtG,
                                              int* __restrict__ gcnt, int nb) {
    const int b = blockIdx.x;
    const int t = threadIdx.x;
    if (b < WT_ROWS) {
        // WtG[n*256+k] = bf16(W[k*HC+n]); n = b, k = t. Exact: inputs bf16-rounded.
        float v = (b < HC) ? W[t * HC + b] : 0.f;
        WtG[b * 256 + t] = (unsigned short)(__float_as_uint(v) >> 16);
    } else {
        if (t < nb) gcnt[t] = 0;
    }
}

// ---------------- bucketed CSR construction (no self loops) ----------------

__global__ __launch_bounds__(256) void k_hist(const int* __restrict__ ei, int E,
                                              int* __restrict__ gcnt, int nb) {
    __shared__ int hist[NBUCK_MAX];
    const int t = threadIdx.x;
    for (int i = t; i < nb; i += 256) hist[i] = 0;
    __syncthreads();
    const int stride = gridDim.x * 256;
    for (int e = blockIdx.x * 256 + t; e < E; e += stride)
        atomicAdd(&hist[ei[E + e] >> BSHIFT], 1);
    __syncthreads();
    for (int i = t; i < nb; i += 256)
        if (hist[i]) atomicAdd(gcnt + i, hist[i]);
}

__global__ __launch_bounds__(1024) void k_bscan(const int* __restrict__ gcnt,
                                                int* __restrict__ boff, int* __restrict__ bcur,
                                                int* __restrict__ row_ptr, int nb, int N) {
    __shared__ int sd[1024];
    int t = threadIdx.x;
    int own = (t < nb) ? gcnt[t] : 0;
    sd[t] = own;
    __syncthreads();
    #pragma unroll
    for (int off = 1; off < 1024; off <<= 1) {
        int v = (t >= off) ? sd[t - off] : 0;
        __syncthreads();
        sd[t] += v;
        __syncthreads();
    }
    if (t < nb) {
        boff[t + 1] = sd[t];
        bcur[t] = sd[t] - own;          // exclusive
        if (t == nb - 1) row_ptr[N] = sd[t];
    }
    if (t == 0) boff[0] = 0;
}

__global__ __launch_bounds__(256) void k_part(const int* __restrict__ ei, int E,
                                              int* __restrict__ bcur, int2* __restrict__ pedge,
                                              int nb) {
    __shared__ int hist[NBUCK_MAX];
    __shared__ int start[NBUCK_MAX];
    const int t = threadIdx.x;
    const int chunk = (E + gridDim.x - 1) / gridDim.x;
    const int c0 = blockIdx.x * chunk;
    const int c1 = min(c0 + chunk, E);
    for (int i = t; i < nb; i += 256) hist[i] = 0;
    __syncthreads();
    for (int e = c0 + t; e < c1; e += 256)
        atomicAdd(&hist[ei[E + e] >> BSHIFT], 1);
    __syncthreads();
    for (int i = t; i < nb; i += 256) {
        int h = hist[i];
        start[i] = h ? atomicAdd(bcur + i, h) : 0;
        hist[i] = 0;                     // reuse as local cursor
    }
    __syncthreads();
    for (int e = c0 + t; e < c1; e += 256) {
        int s = ei[e], d = ei[E + e];
        int b = d >> BSHIFT;
        int pos = start[b] + atomicAdd(&hist[b], 1);
        pedge[pos] = make_int2(s, d);
    }
}

__global__ __launch_bounds__(512) void k_bcsr(const int2* __restrict__ pedge,
                                              const int* __restrict__ boff,
                                              int* __restrict__ row_ptr, int* __restrict__ col,
                                              int N) {
    __shared__ int cnt[BSIZE];
    __shared__ int sc[BSIZE];
    __shared__ int cur[BSIZE];
    const int b  = blockIdx.x;
    const int t  = threadIdx.x;
    const int e0 = boff[b], e1 = boff[b + 1];
    const int base = b << BSHIFT;
    const int nv = min(BSIZE, N - base);
    cnt[t] = 0;
    __syncthreads();
    for (int e = e0 + t; e < e1; e += 512)
        atomicAdd(&cnt[pedge[e].y - base], 1);
    __syncthreads();
    sc[t] = cnt[t];
    __syncthreads();
    #pragma unroll
    for (int off = 1; off < BSIZE; off <<= 1) {
        int v = (t >= off) ? sc[t - off] : 0;
        __syncthreads();
        sc[t] += v;
        __syncthreads();
    }
    if (t < nv) {
        int excl = sc[t] - cnt[t];
        row_ptr[base + t] = e0 + excl;
        cur[t] = excl;
    }
    __syncthreads();
    for (int e = e0 + t; e < e1; e += 512) {
        int2 r = pedge[e];
        int d = r.y - base;
        int pos = e0 + atomicAdd(&cur[d], 1);
        col[pos] = r.x;
    }
}

// ---------------- layer-1: MFMA projection fused with pack ----------------
// 512 threads / 128 rows per block: same 59 KB wt_s (2 blocks/CU) but 16
// waves/CU instead of 8 — staging amortized 2x, load/MFMA/pack phases of
// different waves overlap. Barrier-free K-loop: A-fragments global->reg.
__global__ __launch_bounds__(512) void k_proj1_mfma(
    const float* __restrict__ x, const unsigned short* __restrict__ WtG,
    const float* __restrict__ asrc, const float* __restrict__ adst,
    uint4* __restrict__ xpack, float* __restrict__ aldst, int N)
{
    __shared__ unsigned short wt_s[WT_ROWS * WT_STRIDE];  // 59136 B (reused as f32 vals)
    __shared__ float as_s[HC], ad_s[HC];
    float* vals_s = (float*)wt_s;                          // 128*99*4 = 50688 B < 59136
    const int t  = threadIdx.x;
    const int wv = t >> 6;                                 // 0..7
    const int l  = t & 63;
    const int ln = l & 15;
    const int qd = l >> 4;
    const int rowBase = blockIdx.x * 128;

    #pragma unroll
    for (int i = 0; i < 7; ++i) {
        int f = i * 512 + t;            // uint4 index, 3584 total (32 per row)
        int r = f >> 5, pos = f & 31;
        *(uint4*)(wt_s + r * WT_STRIDE + pos * 8) = ((const uint4*)WtG)[f];
    }
    if (t < HC) { as_s[t] = asrc[t]; ad_s[t] = adst[t]; }
    __syncthreads();

    // my MFMA A-row: rowBase + wv*16 + ln (clamped; pack loop guards gn >= N)
    int gr = rowBase + (wv << 4) + ln; if (gr >= N) gr = N - 1;
    const float* xr = x + (size_t)gr * FIN;

    // load all 8 steps' A-fragments: step s -> cols s*32 + qd*8 .. +7
    short8 afr[8];
    #pragma unroll
    for (int s = 0; s < 8; ++s) {
        float4 v0 = *(const float4*)(xr + s * 32 + qd * 8);
        float4 v1 = *(const float4*)(xr + s * 32 + qd * 8 + 4);
        short8 a;
        a[0] = (short)(__float_as_uint(v0.x) >> 16);
        a[1] = (short)(__float_as_uint(v0.y) >> 16);
        a[2] = (short)(__float_as_uint(v0.z) >> 16);
        a[3] = (short)(__float_as_uint(v0.w) >> 16);
        a[4] = (short)(__float_as_uint(v1.x) >> 16);
        a[5] = (short)(__float_as_uint(v1.y) >> 16);
        a[6] = (short)(__float_as_uint(v1.z) >> 16);
        a[7] = (short)(__float_as_uint(v1.w) >> 16);
        afr[s] = a;
    }

    floatx4 acc[7] = {};
    #pragma unroll
    for (int s = 0; s < 8; ++s) {
        const int k0 = s * 32;
        #pragma unroll
        for (int ct = 0; ct < 7; ++ct) {
            short8 b = *(const short8*)(wt_s + (ct * 16 + ln) * WT_STRIDE + k0 + qd * 8);
            acc[ct] = __builtin_amdgcn_mfma_f32_16x16x32_bf16(afr[s], b, acc[ct], 0, 0, 0);
        }
    }

    __syncthreads();                    // all waves done with wt_s; reuse as vals_s
    // C/D: col = ln, row = qd*4 + r (local row = wv*16 + qd*4 + r, 0..127)
    #pragma unroll
    for (int ct = 0; ct < 7; ++ct) {
        int colg = ct * 16 + ln;
        if (colg < HC) {
            #pragma unroll
            for (int r = 0; r < 4; ++r)
                vals_s[((wv << 4) + (qd << 2) + r) * VS_STRIDE + colg] = acc[ct][r];
        }
    }
    __syncthreads();

    // pack: 128 nodes x 14 heads = 1792 records (consecutive t -> consecutive
    // 16 B records -> coalesced xpack writes)
    for (int p = t; p < 128 * H; p += 512) {
        int nl = p / H, h = p - nl * H;
        int gn = rowBase + nl;
        if (gn >= N) break;
        const float* vp = vals_s + nl * VS_STRIDE + h * C;
        float v[C];
        float s1 = 0.f, s2 = 0.f;
        #pragma unroll
        for (int c2 = 0; c2 < C; ++c2) {
            float f = vp[c2];
            v[c2] = f;
            s1 = fmaf(f, as_s[h * C + c2], s1);
            s2 = fmaf(f, ad_s[h * C + c2], s2);
        }
        uint4 pk;
        pk.x = hpk(v[0], v[1]);
        pk.y = hpk(v[2], v[3]);
        pk.z = hpk(v[4], v[5]);
        pk.w = hpk(v[6], s1 * LOG2E);
        xpack[(size_t)gn * H + h] = pk;
        aldst[(size_t)gn * H + h] = s2 * LOG2E;
    }
}

// ---------------- layer-2 projection + pack: LDS-staged coalesced output ----
// 128 nodes / 128 threads per block: opk 28.7 KB (+Ws/as/ad ~3.5 KB) -> 4
// blocks/CU. Stage records node-major in LDS, flush coalesced; reuse the LDS
// region for the aldst flush.

__global__ __launch_bounds__(128) void k_proj2_pack(
    const float* __restrict__ h1, const float* __restrict__ W,
    const float* __restrict__ asrc, const float* __restrict__ adst,
    uint4* __restrict__ xpack, float* __restrict__ aldst, int N)
{
    __shared__ uint4 opk[P2NODES * H];  // 28672 B (reused as float for aldst)
    __shared__ float Ws[C * HC];
    __shared__ float as_s[HC], ad_s[HC];
    const int t = threadIdx.x;
    for (int i = t; i < C * HC; i += 128) Ws[i] = W[i];
    if (t < HC) { as_s[t] = asrc[t]; ad_s[t] = adst[t]; }
    __syncthreads();

    const int nbase = blockIdx.x * P2NODES;
    const int nv = min(P2NODES, N - nbase);      // live nodes in this block
    const int n = nbase + t;
    float s2r[H];

    if (t < nv) {
        float xr[C];
        #pragma unroll
        for (int c2 = 0; c2 < C; ++c2) xr[c2] = h1[(size_t)n * C + c2];
        #pragma unroll
        for (int h = 0; h < H; ++h) {
            float v[C], s1 = 0.f, s2 = 0.f;
            #pragma unroll
            for (int c2 = 0; c2 < C; ++c2) {
                float acc = 0.f;
                #pragma unroll
                for (int k = 0; k < C; ++k)
                    acc = fmaf(xr[k], Ws[k * HC + h * C + c2], acc);
                v[c2] = acc;
                s1 = fmaf(acc, as_s[h * C + c2], s1);
                s2 = fmaf(acc, ad_s[h * C + c2], s2);
            }
            uint4 pk;
            pk.x = hpk(v[0], v[1]);
            pk.y = hpk(v[2], v[3]);
            pk.z = hpk(v[4], v[5]);
            pk.w = hpk(v[6], s1 * LOG2E);
            opk[t * H + h] = pk;
            s2r[h] = s2 * LOG2E;
        }
    }
    __syncthreads();

    // flush xpack: nv*14 records, coalesced
    {
        uint4* dst = xpack + (size_t)nbase * H;
        const int tot = nv * H;
        for (int i = t; i < tot; i += 128) dst[i] = opk[i];
    }
    __syncthreads();

    // reuse opk region for aldst staging
    float* oal = (float*)opk;
    if (t < nv) {
        #pragma unroll
        for (int h = 0; h < H; ++h) oal[t * H + h] = s2r[h];
    }
    __syncthreads();
    {
        float* dst = aldst + (size_t)nbase * H;
        const int tot = nv * H;
        for (int i = t; i < tot; i += 128) dst[i] = oal[i];
    }
}

// ---------------- fused aggregation: ONE WAVE PER NODE (r6 proven form) ----
// lane = e4*16 + h: e4 in 0..3 = edge slot, h in 0..15 = head (h<14 active).
// Fixed shift K = leaky(ld+2) makes softmax state LINEAR: partial den sums
// and partial channel-maxes combine across edge slots via shfl_xor(16,32);
// head-mean then reduces via shfl_xor(1,2,4,8). No LDS, no __syncthreads.
// Prefetch uses min(...,last) clamps: tail over-prefetch re-reads the cached
// last record instead of gathering random extra lines (r9 lesson: unclamped
// cost +33 MB FETCH and +3 us).
#define AGG_STEP(DEN, REC)                                              \
    {                                                                   \
        float l = hhi((REC).w) + ld;                                    \
        float p = __builtin_amdgcn_exp2f(fmaxf(l, 0.2f * l) - K);       \
        DEN += p;                                                       \
        _Float16 ph = (_Float16)p;                                      \
        h2 p2 = { ph, ph };                                             \
        m0 = __builtin_elementwise_max(m0, p2 * u2h((REC).x));          \
        m1 = __builtin_elementwise_max(m1, p2 * u2h((REC).y));          \
        m2 = __builtin_elementwise_max(m2, p2 * u2h((REC).z));          \
        m3 = __builtin_elementwise_max(m3, p2 * u2h((REC).w));          \
    }

template<int LAYER>
__global__ __launch_bounds__(256) void k_agg(
    const int* __restrict__ row_ptr, const int* __restrict__ col,
    const uint4* __restrict__ xpack, const float* __restrict__ aldst,
    const float* __restrict__ bias,
    float* __restrict__ h1, float* __restrict__ out, int N)
{
    const int t    = threadIdx.x;
    const int lane = t & 63;
    const int e4   = lane >> 4;          // edge slot 0..3
    const int h    = lane & 15;          // head slot (active if < 14)
    const int n    = blockIdx.x * 4 + (t >> 6);
    const bool act = (h < H) && (n < N);

    float den = 0.f, den2 = 0.f;
    h2 m0 = u2h(0xFC00FC00u), m1 = m0, m2 = m0, m3 = m0;   // -inf packed
    float ld = 0.f, K = 0.f;

    if (act) {
        const int e0  = row_ptr[n];
        const int deg = row_ptr[n + 1] - e0;
        ld = aldst[(size_t)n * H + h];                     // already * log2e
        float kb = ld + 2.0f * LOG2E;
        K = fmaxf(kb, 0.2f * kb);                          // leaky(ld+2), log2 domain

        if (e4 == 0) {                                     // implicit self loop (once)
            uint4 pk = xpack[(size_t)n * H + h];
            float l = hhi(pk.w) + ld;
            float p = __builtin_amdgcn_exp2f(fmaxf(l, 0.2f * l) - K);
            den = p;
            _Float16 ph = (_Float16)p;
            h2 p2 = { ph, ph };
            m0 = p2 * u2h(pk.x);
            m1 = p2 * u2h(pk.y);
            m2 = p2 * u2h(pk.z);
            m3 = p2 * u2h(pk.w);                           // hi half ignored later
        }

        if (deg > 0) {
            const int last = deg - 1;
            int i = e4;                                    // edges i = e4 + 4k
            int c0 = col[e0 + min(i,      last)];
            int c1 = col[e0 + min(i + 4,  last)];
            uint4 r0 = xpack[(size_t)c0 * H + h];
            uint4 r1 = xpack[(size_t)c1 * H + h];
            c0 = col[e0 + min(i + 8,  last)];
            c1 = col[e0 + min(i + 12, last)];
            for (; i < deg; i += 8) {
                uint4 curA = r0, curB = r1;
                r0 = xpack[(size_t)c0 * H + h];
                r1 = xpack[(size_t)c1 * H + h];
                c0 = col[e0 + min(i + 16, last)];
                c1 = col[e0 + min(i + 20, last)];
                AGG_STEP(den,  curA);                      // edge i
                if (i + 4 < deg) AGG_STEP(den2, curB);     // edge i+4
            }
        }
    }
    den += den2;

    // ---- combine across edge slots (lanes h, h+16, h+32, h+48) ----
    den += __shfl_xor(den, 16, 64);
    den += __shfl_xor(den, 32, 64);
    m0 = hshfl_max(m0, 16); m0 = hshfl_max(m0, 32);
    m1 = hshfl_max(m1, 16); m1 = hshfl_max(m1, 32);
    m2 = hshfl_max(m2, 16); m2 = hshfl_max(m2, 32);
    m3 = hshfl_max(m3, 16); m3 = hshfl_max(m3, 32);

    float v[C];
    if (act) {
        float rd = 1.f / den;                              // den >= p_self > 0
        v[0] = (float)m0.x * rd; v[1] = (float)m0.y * rd;
        v[2] = (float)m1.x * rd; v[3] = (float)m1.y * rd;
        v[4] = (float)m2.x * rd; v[5] = (float)m2.y * rd;
        v[6] = (float)m3.x * rd;
    } else {
        #pragma unroll
        for (int c = 0; c < C; ++c) v[c] = 0.f;
    }

    // ---- head mean across 16-lane group ----
    #pragma unroll
    for (int off = 1; off <= 8; off <<= 1) {
        #pragma unroll
        for (int c = 0; c < C; ++c) v[c] += __shfl_xor(v[c], off, 64);
    }

    if (n >= N) return;
    if (LAYER == 1) {
        if (lane < C) {
            float myv = v[0];
            #pragma unroll
            for (int c = 1; c < C; ++c) if (lane == c) myv = v[c];
            h1[(size_t)n * C + lane] = fmaxf(myv * (1.f / H) + bias[lane], 0.f);
        }
    } else {
        float o[C];
        #pragma unroll
        for (int c = 0; c < C; ++c) o[c] = v[c] * (1.f / H) + bias[c];
        float mv = o[0];
        #pragma unroll
        for (int c = 1; c < C; ++c) mv = fmaxf(mv, o[c]);
        float lse = 0.f;
        #pragma unroll
        for (int c = 0; c < C; ++c) lse += __expf(o[c] - mv);
        lse = logf(lse);
        if (lane < C) {
            float myo = o[0];
            #pragma unroll
            for (int c = 1; c < C; ++c) if (lane == c) myo = o[c];
            out[(size_t)n * C + lane] = myo - mv - lse;
        }
    }
}

// ---------------- launch ----------------

static inline size_t align16(size_t v) { return (v + 15) & ~(size_t)15; }

extern "C" void kernel_launch(void* const* d_in, const int* in_sizes, int n_in,
                              void* d_out, int out_size, void* d_ws, size_t ws_size,
                              hipStream_t stream)
{
    const float* x     = (const float*)d_in[0];
    const int*   ei    = (const int*)d_in[1];
    const float* W1    = (const float*)d_in[2];
    const float* asrc1 = (const float*)d_in[3];
    const float* adst1 = (const float*)d_in[4];
    const float* b1    = (const float*)d_in[5];
    const float* W2    = (const float*)d_in[6];
    const float* asrc2 = (const float*)d_in[7];
    const float* adst2 = (const float*)d_in[8];
    const float* b2    = (const float*)d_in[9];

    const int N  = in_sizes[0] / FIN;   // 100000
    const int E  = in_sizes[1] / 2;     // 1600000
    const int nb = (N + BSIZE - 1) >> BSHIFT;   // 196

    char* w = (char*)d_ws;
    uint4* xpack   = (uint4*)w; w += align16((size_t)N * H * 16);   // 22.4 MB
    int2*  pedge   = (int2*)w;  w += align16((size_t)E * 8);        // 12.8 MB
    float* aldst   = (float*)w; w += align16((size_t)N * H * 4);    //  5.6 MB
    float* h1      = (float*)w; w += align16((size_t)N * C * 4);    //  2.8 MB
    int*   row_ptr = (int*)w;   w += align16((size_t)(N + 1) * 4);
    int*   col     = (int*)w;   w += align16((size_t)E * 4);        //  6.4 MB
    int*   gcnt    = (int*)w;   w += align16((size_t)nb * 4);
    int*   boff    = (int*)w;   w += align16((size_t)(nb + 1) * 4);
    int*   bcur    = (int*)w;   w += align16((size_t)nb * 4);
    unsigned short* WtG = (unsigned short*)w; w += align16((size_t)WT_ROWS * FIN * 2);

    const int gAgg  = (N + 3) / 4;              // one wave per node, 4 waves/block
    const int gMfma = (N + 127) / 128;          // 128 rows per block
    const int gP2   = (N + P2NODES - 1) / P2NODES;

    // ---- prep (convW + gcnt zero, one launch) + bucketed CSR build ----
    k_prep<<<WT_ROWS + 1, 256, 0, stream>>>(W1, WtG, gcnt, nb);
    k_hist<<<256, 256, 0, stream>>>(ei, E, gcnt, nb);
    k_bscan<<<1, 1024, 0, stream>>>(gcnt, boff, bcur, row_ptr, nb, N);
    k_part<<<256, 256, 0, stream>>>(ei, E, bcur, pedge, nb);
    k_bcsr<<<nb, 512, 0, stream>>>(pedge, boff, row_ptr, col, N);

    // ---- layer 1 ----
    k_proj1_mfma<<<gMfma, 512, 0, stream>>>(x, WtG, asrc1, adst1, xpack, aldst, N);
    k_agg<1><<<gAgg, 256, 0, stream>>>(row_ptr, col, xpack, aldst, b1,
                                       h1, (float*)d_out, N);
    // ---- layer 2 ----
    k_proj2_pack<<<gP2, 128, 0, stream>>>(h1, W2, asrc2, adst2, xpack, aldst, N);
    k_agg<2><<<gAgg, 256, 0, stream>>>(row_ptr, col, xpack, aldst, b2,
                                       h1, (float*)d_out, N);
}